// Round 9
// baseline (390.484 us; speedup 1.0000x reference)
//
#include <hip/hip_runtime.h>
#include <hip/hip_bf16.h>
#include <math.h>

#define NEG_SLOPE 0.2f

typedef _Float16 half8 __attribute__((ext_vector_type(8)));
typedef _Float16 half4 __attribute__((ext_vector_type(4)));
typedef _Float16 half2v __attribute__((ext_vector_type(2)));
typedef float f32x4 __attribute__((ext_vector_type(4)));

__device__ __forceinline__ float lrelu(float x){ return fmaxf(x, NEG_SLOPE * x); }

// ---------------- CSR build (XCD-partitioned by dst range) ----------------
__global__ void hist_kernel(const int* __restrict__ dst, int E,
                            int* __restrict__ deg, int rangeSize){
  const int x   = blockIdx.x & 7;
  const int gb  = blockIdx.x >> 3;
  const int nGB = gridDim.x >> 3;
  const int lo = x * rangeSize, hi = lo + rangeSize;
  const int stride = nGB * blockDim.x;
  for (int i = gb * blockDim.x + threadIdx.x; i < E; i += stride){
    int d = dst[i];
    if (d >= lo && d < hi) atomicAdd(&deg[d], 1);
  }
}

__global__ void scan1_kernel(const int* __restrict__ deg, int N,
                             int* __restrict__ rowptr, int* __restrict__ bsum){
  __shared__ int sdata[256];
  int t = threadIdx.x;
  int base = blockIdx.x * 1024;
  int v[4];
  int run = 0;
#pragma unroll
  for (int j = 0; j < 4; ++j){
    int idx = base + t*4 + j;
    int d = (idx < N) ? deg[idx] : 0;
    run += d;
    v[j] = run;
  }
  sdata[t] = run;
  __syncthreads();
  for (int off = 1; off < 256; off <<= 1){
    int x = (t >= off) ? sdata[t - off] : 0;
    __syncthreads();
    sdata[t] += x;
    __syncthreads();
  }
  int prev = (t > 0) ? sdata[t-1] : 0;
#pragma unroll
  for (int j = 0; j < 4; ++j){
    int idx = base + t*4 + j;
    if (idx < N) rowptr[idx + 1] = v[j] + prev;
  }
  if (t == 255) bsum[blockIdx.x] = sdata[255];
}

__global__ void scan2_kernel(int* __restrict__ bsum, int nb){
  if (threadIdx.x == 0 && blockIdx.x == 0){
    int run = 0;
    for (int i = 0; i < nb; ++i){ int x = bsum[i]; bsum[i] = run; run += x; }
  }
}

// also fills cursor[] = final rowptr[] so scatter can atomicAdd it directly
__global__ void scan3_kernel(int* __restrict__ rowptr, const int* __restrict__ bsum,
                             int* __restrict__ cursor, int N){
  int i = blockIdx.x * blockDim.x + threadIdx.x;
  if (i == 0){ rowptr[0] = 0; cursor[0] = 0; }
  if (i < N){
    int v = rowptr[i + 1] + bsum[i >> 10];
    rowptr[i + 1] = v;
    cursor[i + 1] = v;
  }
}

__global__ void scatter_kernel(const int* __restrict__ src, const int* __restrict__ dst, int E,
                               int* __restrict__ cursor, int* __restrict__ csr_src, int rangeSize){
  const int x   = blockIdx.x & 7;
  const int gb  = blockIdx.x >> 3;
  const int nGB = gridDim.x >> 3;
  const int lo = x * rangeSize, hi = lo + rangeSize;
  const int stride = nGB * blockDim.x;
  for (int i = gb * blockDim.x + threadIdx.x; i < E; i += stride){
    int d = dst[i];
    if (d >= lo && d < hi){
      int pos = atomicAdd(&cursor[d], 1);
      csr_src[pos] = src[i];
    }
  }
}

// ---------------- prep: Wt (f16 transposed) for both layers + w2s/w2d ----------------
__global__ void prep_kernel(const float* __restrict__ W1, const float* __restrict__ W2,
                            const float* __restrict__ as2, const float* __restrict__ ad2,
                            _Float16* __restrict__ Wt1, _Float16* __restrict__ Wt2,
                            float* __restrict__ w2s, float* __restrict__ w2d){
  int t = threadIdx.x;
  if (blockIdx.x < 2){
    const float* W = blockIdx.x ? W2 : W1;
    _Float16* Wt = blockIdx.x ? Wt2 : Wt1;
    for (int i = 0; i < 64; ++i){
      int e = i*256 + t;
      int k = e >> 7, c = e & 127;
      Wt[c*128 + k] = (_Float16)W[e];
    }
  } else {
    if (t < 128){
      float ps = 0.f, pd = 0.f;
      for (int c = 0; c < 128; ++c){
        float w = W2[t*128 + c];
        ps += w * as2[c];
        pd += w * ad2[c];
      }
      w2s[t] = ps;
      w2d[t] = pd;
    }
  }
}

// ---------------- MFMA f16 GEMM: h[N,128] = A[N,128] @ W[128,128] ----------------
template<int ALPHA_H, bool CASTF32, bool OUTF32>
__launch_bounds__(256, 2)
__global__ void gemm_mfma(const void* __restrict__ Aptr, const _Float16* __restrict__ Wt,
                          void* __restrict__ outp, const float* __restrict__ bias,
                          const float* __restrict__ a_src, const float* __restrict__ a_dst,
                          float* __restrict__ alpha_s, float* __restrict__ alpha_d, int N){
  __shared__ __align__(16) _Float16 Xs[128*128];
  __shared__ __align__(16) _Float16 Ws[128*128];
  __shared__ float apart[2][128][2];
  const int t = threadIdx.x;
  const int lane = t & 63;
  const int w = t >> 6;
  const int wr = w & 1, wc = w >> 1;
  const int rowBase = blockIdx.x * 128;
  const int lrow = lane & 15, lk = lane >> 4;

  if (CASTF32){
    const float* A = (const float*)Aptr;
#pragma unroll
    for (int p = 0; p < 16; ++p){
      int flat = p*256 + t;
      int row = flat >> 5, seg = flat & 31;
      int gr = rowBase + row;
      float4 v = (gr < N) ? *(const float4*)(A + (size_t)gr*128 + seg*4)
                          : make_float4(0.f,0.f,0.f,0.f);
      half4 hv = {(_Float16)v.x, (_Float16)v.y, (_Float16)v.z, (_Float16)v.w};
      int byt = (row*256 + seg*8) ^ ((row & 7) << 4);
      *(half4*)((char*)Xs + byt) = hv;
    }
  } else {
    const _Float16* A = (const _Float16*)Aptr;
#pragma unroll
    for (int p = 0; p < 8; ++p){
      int flat = p*256 + t;
      int row = flat >> 4, seg = flat & 15;
      int gr = rowBase + row;
      int4 v = (gr < N) ? *(const int4*)(A + (size_t)gr*128 + seg*8)
                        : make_int4(0,0,0,0);
      int byt = (row*256 + seg*16) ^ ((row & 7) << 4);
      *(int4*)((char*)Xs + byt) = v;
    }
  }
#pragma unroll
  for (int p = 0; p < 8; ++p){
    int flat = p*256 + t;
    int row = flat >> 4, seg = flat & 15;
    int4 v = *(const int4*)(Wt + row*128 + seg*8);
    int byt = (row*256 + seg*16) ^ ((row & 7) << 4);
    *(int4*)((char*)Ws + byt) = v;
  }
  __syncthreads();

  f32x4 acc[4][4];
#pragma unroll
  for (int mf = 0; mf < 4; ++mf)
#pragma unroll
    for (int nf = 0; nf < 4; ++nf) acc[mf][nf] = (f32x4){0.f,0.f,0.f,0.f};

#pragma unroll
  for (int ks = 0; ks < 4; ++ks){
    const int kbyte = ks*64 + lk*16;
    half8 b[4], a[4];
#pragma unroll
    for (int nf = 0; nf < 4; ++nf){
      int row = wr*64 + nf*16 + lrow;
      b[nf] = *(const half8*)((const char*)Xs + ((row*256 + kbyte) ^ ((row & 7) << 4)));
    }
#pragma unroll
    for (int mf = 0; mf < 4; ++mf){
      int col = wc*64 + mf*16 + lrow;
      a[mf] = *(const half8*)((const char*)Ws + ((col*256 + kbyte) ^ ((col & 7) << 4)));
    }
#pragma unroll
    for (int mf = 0; mf < 4; ++mf)
#pragma unroll
      for (int nf = 0; nf < 4; ++nf)
        acc[mf][nf] = __builtin_amdgcn_mfma_f32_16x16x32_f16(a[mf], b[nf], acc[mf][nf], 0, 0, 0);
  }

  if (OUTF32){
    float* outf = (float*)outp;
    float4 b4[4];
#pragma unroll
    for (int mf = 0; mf < 4; ++mf)
      b4[mf] = *(const float4*)(bias + wc*64 + mf*16 + lk*4);
#pragma unroll
    for (int nf = 0; nf < 4; ++nf){
      int row = rowBase + wr*64 + nf*16 + lrow;
      if (row < N){
#pragma unroll
        for (int mf = 0; mf < 4; ++mf){
          int col = wc*64 + mf*16 + lk*4;
          f32x4 v = acc[mf][nf];
          float4 st = make_float4(v.x + b4[mf].x, v.y + b4[mf].y, v.z + b4[mf].z, v.w + b4[mf].w);
          *(float4*)(outf + (size_t)row*128 + col) = st;
        }
      }
    }
  } else {
    _Float16* hout = (_Float16*)outp;
#pragma unroll
    for (int nf = 0; nf < 4; ++nf){
      int row = rowBase + wr*64 + nf*16 + lrow;
      if (row < N){
#pragma unroll
        for (int mf = 0; mf < 4; ++mf){
          int col = wc*64 + mf*16 + lk*4;
          f32x4 v = acc[mf][nf];
          half4 hv = {(_Float16)v.x, (_Float16)v.y, (_Float16)v.z, (_Float16)v.w};
          *(half4*)(hout + (size_t)row*128 + col) = hv;
        }
      }
    }
  }

  if (ALPHA_H > 0){
    float4 as4[4], ad4[4];
#pragma unroll
    for (int mf = 0; mf < 4; ++mf){
      int cb = wc*64 + mf*16 + lk*4;
      as4[mf] = *(const float4*)(a_src + cb);
      ad4[mf] = *(const float4*)(a_dst + cb);
    }
    if (ALPHA_H == 8){
#pragma unroll
      for (int nf = 0; nf < 4; ++nf){
        int row = rowBase + wr*64 + nf*16 + lrow;
#pragma unroll
        for (int mf = 0; mf < 4; ++mf){
          f32x4 v = acc[mf][nf];
          float ps = v.x*as4[mf].x + v.y*as4[mf].y + v.z*as4[mf].z + v.w*as4[mf].w;
          float pd = v.x*ad4[mf].x + v.y*ad4[mf].y + v.z*ad4[mf].z + v.w*ad4[mf].w;
          ps += __shfl_xor(ps, 16); ps += __shfl_xor(ps, 32);
          pd += __shfl_xor(pd, 16); pd += __shfl_xor(pd, 32);
          if (lane < 16 && row < N){
            int head = wc*4 + mf;
            alpha_s[(size_t)row*8 + head] = ps;
            alpha_d[(size_t)row*8 + head] = pd;
          }
        }
      }
    } else {
#pragma unroll
      for (int nf = 0; nf < 4; ++nf){
        float ps = 0.f, pd = 0.f;
#pragma unroll
        for (int mf = 0; mf < 4; ++mf){
          f32x4 v = acc[mf][nf];
          ps += v.x*as4[mf].x + v.y*as4[mf].y + v.z*as4[mf].z + v.w*as4[mf].w;
          pd += v.x*ad4[mf].x + v.y*ad4[mf].y + v.z*ad4[mf].z + v.w*ad4[mf].w;
        }
        ps += __shfl_xor(ps, 16); ps += __shfl_xor(ps, 32);
        pd += __shfl_xor(pd, 16); pd += __shfl_xor(pd, 32);
        if (lane < 16){
          int rl = wr*64 + nf*16 + lane;
          apart[0][rl][wc] = ps;
          apart[1][rl][wc] = pd;
        }
      }
      __syncthreads();
      if (wc == 0){
        int rl = wr*64 + lane;
        int row = rowBase + rl;
        if (row < N){
          alpha_s[row] = apart[0][rl][0] + apart[0][rl][1];
          alpha_d[row] = apart[1][rl][0] + apart[1][rl][1];
        }
      }
    }
  }
}

// ---------------- two-phase softmax-aggregation (wave per node), f32 numerics ----------------
// Phase 1: lane (edge,head) computes ONE f32 ex (no 16x redundancy).
// Phase 2: 4 edge-groups x 16 lanes; ex/src broadcast via __shfl.
// CRITICAL: phase-2 trip count is wave-uniform (limr rounded up to x4) so every
// __shfl executes with all 64 lanes active — divergent shfl reads inactive lanes
// (undefined/zero on CDNA) and was the R7/R8 correctness bug. Padding slots have
// exf=0, sv=n from phase 1, so they contribute nothing.
template<int H, bool LAYER1>
__launch_bounds__(256)
__global__ void agg_kernel(const _Float16* __restrict__ hb, const float* __restrict__ alpha_s,
                           const float* __restrict__ alpha_d,
                           const int* __restrict__ rowptr, const int* __restrict__ csr_src,
                           const float* __restrict__ bias,
                           const float* __restrict__ w2s, const float* __restrict__ w2d,
                           _Float16* __restrict__ outh,
                           float* __restrict__ as2, float* __restrict__ ad2, int N){
  const int wid = threadIdx.x >> 6, lane = threadIdx.x & 63;
  const int n = blockIdx.x * 4 + wid;
  if (n >= N) return;
  const int start = rowptr[n];
  const int deg = rowptr[n + 1] - start;
  const int T = deg + 1;                    // + self loop (slot j == deg)

  const int g  = lane >> 4;
  const int l  = lane & 15;
  const int ch = l * 8;
  const int hm = (H == 8) ? (l >> 1) : 0;

  const int p1e = (H == 8) ? (lane >> 3) : lane;   // phase-1 edge slot in chunk
  const int p1h = (H == 8) ? (lane & 7) : 0;       // phase-1 head
  const int CH  = (H == 8) ? 8 : 64;               // edges per chunk

  const float ad1 = alpha_d[(size_t)n*H + p1h];

  float acc[8];
#pragma unroll
  for (int k = 0; k < 8; ++k) acc[k] = 0.f;
  float ssum_l = 0.f;

  for (int base = 0; base < T; base += CH){
    // ---- phase 1: one ex per (edge, head)
    int j = base + p1e;
    float exf = 0.f;
    int sv = n;
    if (j < T){
      if (j < deg) sv = csr_src[start + j];
      float e = alpha_s[(size_t)sv*H + p1h] + ad1;
      e = fmaxf(e, NEG_SLOPE * e);          // leaky relu
      exf = __expf(e);
      ssum_l += exf;
    }
    // ---- phase 2: gather + accumulate (uniform trip count across groups!)
    int lim  = min(CH, T - base);
    int limr = (lim + 3) & ~3;              // round up to multiple of 4
    for (int jj = g; jj < limr; jj += 4){
      int srcl = (H == 8) ? (jj*8 + hm) : jj;
      int s = __shfl(sv, srcl);
      float ex = __shfl(exf, srcl);         // 0 for padding slots
      int4 hv = *(const int4*)(hb + (s << 7) + ch);
      half2v h0 = __builtin_bit_cast(half2v, hv.x);
      half2v h1 = __builtin_bit_cast(half2v, hv.y);
      half2v h2 = __builtin_bit_cast(half2v, hv.z);
      half2v h3 = __builtin_bit_cast(half2v, hv.w);
      acc[0] += (float)h0.x * ex; acc[1] += (float)h0.y * ex;
      acc[2] += (float)h1.x * ex; acc[3] += (float)h1.y * ex;
      acc[4] += (float)h2.x * ex; acc[5] += (float)h2.y * ex;
      acc[6] += (float)h3.x * ex; acc[7] += (float)h3.y * ex;
    }
  }

  // ---- ssum reduce
  if (H == 8){
    ssum_l += __shfl_xor(ssum_l, 8);
    ssum_l += __shfl_xor(ssum_l, 16);
    ssum_l += __shfl_xor(ssum_l, 32);     // every lane: ssum of head (lane&7)
  } else {
#pragma unroll
    for (int off = 1; off < 64; off <<= 1) ssum_l += __shfl_xor(ssum_l, off);
  }
  float ssum = __shfl(ssum_l, hm);

  // ---- acc reduce across the 4 edge groups
#pragma unroll
  for (int k = 0; k < 8; ++k){
    acc[k] += __shfl_xor(acc[k], 16);
    acc[k] += __shfl_xor(acc[k], 32);
  }

  if (lane < 16){
    float inv = 1.0f / ssum;
    float o[8];
#pragma unroll
    for (int k = 0; k < 8; ++k) o[k] = acc[k] * inv;
    if (LAYER1){
      float4 b0 = *(const float4*)(bias + ch);
      float4 b1 = *(const float4*)(bias + ch + 4);
      float bb[8] = {b0.x,b0.y,b0.z,b0.w,b1.x,b1.y,b1.z,b1.w};
#pragma unroll
      for (int k = 0; k < 8; ++k){
        float v = o[k] + bb[k];
        o[k] = (v > 0.f) ? v : expm1f(v);             // ELU
      }
    }
    half8 ho;
#pragma unroll
    for (int k = 0; k < 8; ++k) ho[k] = (_Float16)o[k];
    *(half8*)(outh + (size_t)n*128 + ch) = ho;

    if (LAYER1){
      float4 s0 = *(const float4*)(w2s + ch);
      float4 s1 = *(const float4*)(w2s + ch + 4);
      float4 d0 = *(const float4*)(w2d + ch);
      float4 d1 = *(const float4*)(w2d + ch + 4);
      float ps = o[0]*s0.x + o[1]*s0.y + o[2]*s0.z + o[3]*s0.w
               + o[4]*s1.x + o[5]*s1.y + o[6]*s1.z + o[7]*s1.w;
      float pd = o[0]*d0.x + o[1]*d0.y + o[2]*d0.z + o[3]*d0.w
               + o[4]*d1.x + o[5]*d1.y + o[6]*d1.z + o[7]*d1.w;
#pragma unroll
      for (int off = 1; off < 16; off <<= 1){
        ps += __shfl_xor(ps, off);
        pd += __shfl_xor(pd, off);
      }
      if (l == 0){
        as2[n] = ps;
        ad2[n] = pd;
      }
    }
  }
}

extern "C" void kernel_launch(void* const* d_in, const int* in_sizes, int n_in,
                              void* d_out, int out_size, void* d_ws, size_t ws_size,
                              hipStream_t stream){
  const float* x      = (const float*)d_in[0];
  const int*   ei     = (const int*)  d_in[1];
  const float* W1     = (const float*)d_in[2];
  const float* a_src1 = (const float*)d_in[3];
  const float* a_dst1 = (const float*)d_in[4];
  const float* b1     = (const float*)d_in[5];
  const float* W2     = (const float*)d_in[6];
  const float* a_src2 = (const float*)d_in[7];
  const float* a_dst2 = (const float*)d_in[8];
  const float* b2     = (const float*)d_in[9];
  float* out = (float*)d_out;

  const int N = in_sizes[0] / 128;
  const int E = in_sizes[1] / 2;
  const int* src = ei;
  const int* dst = ei + E;

  char* ws = (char*)d_ws;
  size_t off = 0;
  auto alloc = [&](size_t bytes) -> void* {
    void* p = ws + off;
    off += (bytes + 255) & ~(size_t)255;
    return p;
  };
  _Float16* hb   = (_Float16*)alloc((size_t)N * 128 * 2);  // layer-1 h, reused as agg2
  _Float16* act  = (_Float16*)alloc((size_t)N * 128 * 2);  // layer-1 output (ELU'd)
  float* asb     = (float*)alloc((size_t)N * 8 * 4);
  float* adb     = (float*)alloc((size_t)N * 8 * 4);
  float* as2     = (float*)alloc((size_t)N * 4);
  float* ad2     = (float*)alloc((size_t)N * 4);
  _Float16* Wt1  = (_Float16*)alloc(16384 * 2);
  _Float16* Wt2  = (_Float16*)alloc(16384 * 2);
  float* w2s     = (float*)alloc(128 * 4);
  float* w2d     = (float*)alloc(128 * 4);
  int*   csr     = (int*)  alloc((size_t)E * 4);
  int*   rowptr  = (int*)  alloc((size_t)(N + 1) * 4);
  int*   cursor  = (int*)  alloc((size_t)(N + 1) * 4);
  int*   deg     = (int*)  alloc((size_t)N * 4);
  int*   bsum    = (int*)  alloc(4096);

  hipMemsetAsync(deg, 0, (size_t)N * 4, stream);

  const int nb = (N + 1023) / 1024;
  const int rangeSize = (N + 7) / 8;
  prep_kernel   <<<3, 256, 0, stream>>>(W1, W2, a_src2, a_dst2, Wt1, Wt2, w2s, w2d);
  hist_kernel   <<<2048, 256, 0, stream>>>(dst, E, deg, rangeSize);
  scan1_kernel  <<<nb, 256, 0, stream>>>(deg, N, rowptr, bsum);
  scan2_kernel  <<<1, 64, 0, stream>>>(bsum, nb);
  scan3_kernel  <<<(N + 255)/256, 256, 0, stream>>>(rowptr, bsum, cursor, N);
  scatter_kernel<<<2048, 256, 0, stream>>>(src, dst, E, cursor, csr, rangeSize);

  const int gBlocks  = (N + 127) / 128;
  const int nBlocks4 = (N + 3) / 4;

  // layer 1: h1 = x@W1 (f16 MFMA) + alpha1 epilogue
  gemm_mfma<8, true, false><<<gBlocks, 256, 0, stream>>>(
      x, Wt1, hb, nullptr, a_src1, a_dst1, asb, adb, N);
  // agg1: act = ELU(P1 . h1 + b1), fused alpha2 = act . (W2^T a2)
  agg_kernel<8, true><<<nBlocks4, 256, 0, stream>>>(
      hb, asb, adb, rowptr, csr, b1, w2s, w2d, act, as2, ad2, N);
  // agg2 = P2 . act (normalized), into hb (dead)
  agg_kernel<1, false><<<nBlocks4, 256, 0, stream>>>(
      act, as2, ad2, rowptr, csr, nullptr, nullptr, nullptr, hb, nullptr, nullptr, N);
  // out = agg2 @ W2 + b2 (f32 out)
  gemm_mfma<0, false, true><<<gBlocks, 256, 0, stream>>>(
      hb, Wt2, out, b2, nullptr, nullptr, nullptr, nullptr, N);
}

// Round 10
// 375.504 us; speedup vs baseline: 1.0399x; 1.0399x over previous
//
#include <hip/hip_runtime.h>
#include <hip/hip_bf16.h>
#include <math.h>

#define NEG_SLOPE 0.2f

typedef _Float16 half8 __attribute__((ext_vector_type(8)));
typedef _Float16 half4 __attribute__((ext_vector_type(4)));
typedef _Float16 half2v __attribute__((ext_vector_type(2)));
typedef float f32x4 __attribute__((ext_vector_type(4)));

__device__ __forceinline__ float lrelu(float x){ return fmaxf(x, NEG_SLOPE * x); }

// ---------------- CSR build (XCD-partitioned by dst range) ----------------
__global__ void hist_kernel(const int* __restrict__ dst, int E,
                            int* __restrict__ deg, int rangeSize){
  const int x   = blockIdx.x & 7;
  const int gb  = blockIdx.x >> 3;
  const int nGB = gridDim.x >> 3;
  const int lo = x * rangeSize, hi = lo + rangeSize;
  const int stride = nGB * blockDim.x;
  for (int i = gb * blockDim.x + threadIdx.x; i < E; i += stride){
    int d = dst[i];
    if (d >= lo && d < hi) atomicAdd(&deg[d], 1);
  }
}

__global__ void scan1_kernel(const int* __restrict__ deg, int N,
                             int* __restrict__ rowptr, int* __restrict__ bsum){
  __shared__ int sdata[256];
  int t = threadIdx.x;
  int base = blockIdx.x * 1024;
  int v[4];
  int run = 0;
#pragma unroll
  for (int j = 0; j < 4; ++j){
    int idx = base + t*4 + j;
    int d = (idx < N) ? deg[idx] : 0;
    run += d;
    v[j] = run;
  }
  sdata[t] = run;
  __syncthreads();
  for (int off = 1; off < 256; off <<= 1){
    int x = (t >= off) ? sdata[t - off] : 0;
    __syncthreads();
    sdata[t] += x;
    __syncthreads();
  }
  int prev = (t > 0) ? sdata[t-1] : 0;
#pragma unroll
  for (int j = 0; j < 4; ++j){
    int idx = base + t*4 + j;
    if (idx < N) rowptr[idx + 1] = v[j] + prev;
  }
  if (t == 255) bsum[blockIdx.x] = sdata[255];
}

__global__ void scan2_kernel(int* __restrict__ bsum, int nb){
  if (threadIdx.x == 0 && blockIdx.x == 0){
    int run = 0;
    for (int i = 0; i < nb; ++i){ int x = bsum[i]; bsum[i] = run; run += x; }
  }
}

// also fills cursor[] = final rowptr[] so scatter can atomicAdd it directly
__global__ void scan3_kernel(int* __restrict__ rowptr, const int* __restrict__ bsum,
                             int* __restrict__ cursor, int N){
  int i = blockIdx.x * blockDim.x + threadIdx.x;
  if (i == 0){ rowptr[0] = 0; cursor[0] = 0; }
  if (i < N){
    int v = rowptr[i + 1] + bsum[i >> 10];
    rowptr[i + 1] = v;
    cursor[i + 1] = v;
  }
}

__global__ void scatter_kernel(const int* __restrict__ src, const int* __restrict__ dst, int E,
                               int* __restrict__ cursor, int* __restrict__ csr_src, int rangeSize){
  const int x   = blockIdx.x & 7;
  const int gb  = blockIdx.x >> 3;
  const int nGB = gridDim.x >> 3;
  const int lo = x * rangeSize, hi = lo + rangeSize;
  const int stride = nGB * blockDim.x;
  for (int i = gb * blockDim.x + threadIdx.x; i < E; i += stride){
    int d = dst[i];
    if (d >= lo && d < hi){
      int pos = atomicAdd(&cursor[d], 1);
      csr_src[pos] = src[i];
    }
  }
}

// ---------------- prep: Wt (f16 transposed) for both layers + w2s/w2d ----------------
__global__ void prep_kernel(const float* __restrict__ W1, const float* __restrict__ W2,
                            const float* __restrict__ as2, const float* __restrict__ ad2,
                            _Float16* __restrict__ Wt1, _Float16* __restrict__ Wt2,
                            float* __restrict__ w2s, float* __restrict__ w2d){
  int t = threadIdx.x;
  if (blockIdx.x < 2){
    const float* W = blockIdx.x ? W2 : W1;
    _Float16* Wt = blockIdx.x ? Wt2 : Wt1;
    for (int i = 0; i < 64; ++i){
      int e = i*256 + t;
      int k = e >> 7, c = e & 127;
      Wt[c*128 + k] = (_Float16)W[e];
    }
  } else {
    if (t < 128){
      float ps = 0.f, pd = 0.f;
      for (int c = 0; c < 128; ++c){
        float w = W2[t*128 + c];
        ps += w * as2[c];
        pd += w * ad2[c];
      }
      w2s[t] = ps;
      w2d[t] = pd;
    }
  }
}

// ---------------- MFMA f16 GEMM: h[N,128] = A[N,128] @ W[128,128] ----------------
template<int ALPHA_H, bool CASTF32, bool OUTF32>
__launch_bounds__(256, 2)
__global__ void gemm_mfma(const void* __restrict__ Aptr, const _Float16* __restrict__ Wt,
                          void* __restrict__ outp, const float* __restrict__ bias,
                          const float* __restrict__ a_src, const float* __restrict__ a_dst,
                          float* __restrict__ alpha_s, float* __restrict__ alpha_d, int N){
  __shared__ __align__(16) _Float16 Xs[128*128];
  __shared__ __align__(16) _Float16 Ws[128*128];
  __shared__ float apart[2][128][2];
  const int t = threadIdx.x;
  const int lane = t & 63;
  const int w = t >> 6;
  const int wr = w & 1, wc = w >> 1;
  const int rowBase = blockIdx.x * 128;
  const int lrow = lane & 15, lk = lane >> 4;

  if (CASTF32){
    const float* A = (const float*)Aptr;
#pragma unroll
    for (int p = 0; p < 16; ++p){
      int flat = p*256 + t;
      int row = flat >> 5, seg = flat & 31;
      int gr = rowBase + row;
      float4 v = (gr < N) ? *(const float4*)(A + (size_t)gr*128 + seg*4)
                          : make_float4(0.f,0.f,0.f,0.f);
      half4 hv = {(_Float16)v.x, (_Float16)v.y, (_Float16)v.z, (_Float16)v.w};
      int byt = (row*256 + seg*8) ^ ((row & 7) << 4);
      *(half4*)((char*)Xs + byt) = hv;
    }
  } else {
    const _Float16* A = (const _Float16*)Aptr;
#pragma unroll
    for (int p = 0; p < 8; ++p){
      int flat = p*256 + t;
      int row = flat >> 4, seg = flat & 15;
      int gr = rowBase + row;
      int4 v = (gr < N) ? *(const int4*)(A + (size_t)gr*128 + seg*8)
                        : make_int4(0,0,0,0);
      int byt = (row*256 + seg*16) ^ ((row & 7) << 4);
      *(int4*)((char*)Xs + byt) = v;
    }
  }
#pragma unroll
  for (int p = 0; p < 8; ++p){
    int flat = p*256 + t;
    int row = flat >> 4, seg = flat & 15;
    int4 v = *(const int4*)(Wt + row*128 + seg*8);
    int byt = (row*256 + seg*16) ^ ((row & 7) << 4);
    *(int4*)((char*)Ws + byt) = v;
  }
  __syncthreads();

  f32x4 acc[4][4];
#pragma unroll
  for (int mf = 0; mf < 4; ++mf)
#pragma unroll
    for (int nf = 0; nf < 4; ++nf) acc[mf][nf] = (f32x4){0.f,0.f,0.f,0.f};

#pragma unroll
  for (int ks = 0; ks < 4; ++ks){
    const int kbyte = ks*64 + lk*16;
    half8 b[4], a[4];
#pragma unroll
    for (int nf = 0; nf < 4; ++nf){
      int row = wr*64 + nf*16 + lrow;
      b[nf] = *(const half8*)((const char*)Xs + ((row*256 + kbyte) ^ ((row & 7) << 4)));
    }
#pragma unroll
    for (int mf = 0; mf < 4; ++mf){
      int col = wc*64 + mf*16 + lrow;
      a[mf] = *(const half8*)((const char*)Ws + ((col*256 + kbyte) ^ ((col & 7) << 4)));
    }
#pragma unroll
    for (int mf = 0; mf < 4; ++mf)
#pragma unroll
      for (int nf = 0; nf < 4; ++nf)
        acc[mf][nf] = __builtin_amdgcn_mfma_f32_16x16x32_f16(a[mf], b[nf], acc[mf][nf], 0, 0, 0);
  }

  if (OUTF32){
    float* outf = (float*)outp;
    float4 b4[4];
#pragma unroll
    for (int mf = 0; mf < 4; ++mf)
      b4[mf] = *(const float4*)(bias + wc*64 + mf*16 + lk*4);
#pragma unroll
    for (int nf = 0; nf < 4; ++nf){
      int row = rowBase + wr*64 + nf*16 + lrow;
      if (row < N){
#pragma unroll
        for (int mf = 0; mf < 4; ++mf){
          int col = wc*64 + mf*16 + lk*4;
          f32x4 v = acc[mf][nf];
          float4 st = make_float4(v.x + b4[mf].x, v.y + b4[mf].y, v.z + b4[mf].z, v.w + b4[mf].w);
          *(float4*)(outf + (size_t)row*128 + col) = st;
        }
      }
    }
  } else {
    _Float16* hout = (_Float16*)outp;
#pragma unroll
    for (int nf = 0; nf < 4; ++nf){
      int row = rowBase + wr*64 + nf*16 + lrow;
      if (row < N){
#pragma unroll
        for (int mf = 0; mf < 4; ++mf){
          int col = wc*64 + mf*16 + lk*4;
          f32x4 v = acc[mf][nf];
          half4 hv = {(_Float16)v.x, (_Float16)v.y, (_Float16)v.z, (_Float16)v.w};
          *(half4*)(hout + (size_t)row*128 + col) = hv;
        }
      }
    }
  }

  if (ALPHA_H > 0){
    float4 as4[4], ad4[4];
#pragma unroll
    for (int mf = 0; mf < 4; ++mf){
      int cb = wc*64 + mf*16 + lk*4;
      as4[mf] = *(const float4*)(a_src + cb);
      ad4[mf] = *(const float4*)(a_dst + cb);
    }
    if (ALPHA_H == 8){
#pragma unroll
      for (int nf = 0; nf < 4; ++nf){
        int row = rowBase + wr*64 + nf*16 + lrow;
#pragma unroll
        for (int mf = 0; mf < 4; ++mf){
          f32x4 v = acc[mf][nf];
          float ps = v.x*as4[mf].x + v.y*as4[mf].y + v.z*as4[mf].z + v.w*as4[mf].w;
          float pd = v.x*ad4[mf].x + v.y*ad4[mf].y + v.z*ad4[mf].z + v.w*ad4[mf].w;
          ps += __shfl_xor(ps, 16); ps += __shfl_xor(ps, 32);
          pd += __shfl_xor(pd, 16); pd += __shfl_xor(pd, 32);
          if (lane < 16 && row < N){
            int head = wc*4 + mf;
            alpha_s[(size_t)row*8 + head] = ps;
            alpha_d[(size_t)row*8 + head] = pd;
          }
        }
      }
    } else {
#pragma unroll
      for (int nf = 0; nf < 4; ++nf){
        float ps = 0.f, pd = 0.f;
#pragma unroll
        for (int mf = 0; mf < 4; ++mf){
          f32x4 v = acc[mf][nf];
          ps += v.x*as4[mf].x + v.y*as4[mf].y + v.z*as4[mf].z + v.w*as4[mf].w;
          pd += v.x*ad4[mf].x + v.y*ad4[mf].y + v.z*ad4[mf].z + v.w*ad4[mf].w;
        }
        ps += __shfl_xor(ps, 16); ps += __shfl_xor(ps, 32);
        pd += __shfl_xor(pd, 16); pd += __shfl_xor(pd, 32);
        if (lane < 16){
          int rl = wr*64 + nf*16 + lane;
          apart[0][rl][wc] = ps;
          apart[1][rl][wc] = pd;
        }
      }
      __syncthreads();
      if (wc == 0){
        int rl = wr*64 + lane;
        int row = rowBase + rl;
        if (row < N){
          alpha_s[row] = apart[0][rl][0] + apart[0][rl][1];
          alpha_d[row] = apart[1][rl][0] + apart[1][rl][1];
        }
      }
    }
  }
}

// ---------------- softmax-aggregation (R6 structure, 4x unrolled gather) ----------------
// One wave per node; 4 edge-groups x 16 lanes x 8 channels. Self-loop peeled to
// group 3. Main loop: 4 independent csr->alpha->h chains (16 edges/body) to
// maximize outstanding misses; tail loop single. All-f32 softmax numerics.
template<int H, bool LAYER1>
__launch_bounds__(256)
__global__ void agg_kernel(const _Float16* __restrict__ hb, const float* __restrict__ alpha_s,
                           const float* __restrict__ alpha_d,
                           const int* __restrict__ rowptr, const int* __restrict__ csr_src,
                           const float* __restrict__ bias,
                           const float* __restrict__ w2s, const float* __restrict__ w2d,
                           _Float16* __restrict__ outh,
                           float* __restrict__ as2, float* __restrict__ ad2, int N){
  const int wid = threadIdx.x >> 6, lane = threadIdx.x & 63;
  const int n = blockIdx.x * 4 + wid;
  if (n >= N) return;
  const int start = rowptr[n];
  const int deg = rowptr[n + 1] - start;

  const int g  = lane >> 4;
  const int l  = lane & 15;
  const int ch = l * 8;
  const int hm = (H == 8) ? (l >> 1) : 0;
  const float ad_m = alpha_d[(size_t)n*H + hm];

  float acc[8];
#pragma unroll
  for (int k = 0; k < 8; ++k) acc[k] = 0.f;
  float ssum = 0.f;

  auto edge = [&](int s, float ex){
    int4 hv = *(const int4*)(hb + ((size_t)s << 7) + ch);
    half2v h0 = __builtin_bit_cast(half2v, hv.x);
    half2v h1 = __builtin_bit_cast(half2v, hv.y);
    half2v h2 = __builtin_bit_cast(half2v, hv.z);
    half2v h3 = __builtin_bit_cast(half2v, hv.w);
    acc[0] += (float)h0.x * ex; acc[1] += (float)h0.y * ex;
    acc[2] += (float)h1.x * ex; acc[3] += (float)h1.y * ex;
    acc[4] += (float)h2.x * ex; acc[5] += (float)h2.y * ex;
    acc[6] += (float)h3.x * ex; acc[7] += (float)h3.y * ex;
    ssum += ex;
  };

  // self-loop (group 3)
  if (g == 3){
    float ex = __expf(lrelu(alpha_s[(size_t)n*H + hm] + ad_m));
    edge(n, ex);
  }

  int i = g;
  // 4x unrolled: 4 independent csr->alpha->h chains in flight (16 edges/body)
  for (; i + 12 < deg; i += 16){
    int s0 = csr_src[start + i];
    int s1 = csr_src[start + i + 4];
    int s2 = csr_src[start + i + 8];
    int s3 = csr_src[start + i + 12];
    float a0 = alpha_s[(size_t)s0*H + hm];
    float a1 = alpha_s[(size_t)s1*H + hm];
    float a2 = alpha_s[(size_t)s2*H + hm];
    float a3 = alpha_s[(size_t)s3*H + hm];
    float e0 = __expf(lrelu(a0 + ad_m));
    float e1 = __expf(lrelu(a1 + ad_m));
    float e2 = __expf(lrelu(a2 + ad_m));
    float e3 = __expf(lrelu(a3 + ad_m));
    edge(s0, e0); edge(s1, e1); edge(s2, e2); edge(s3, e3);
  }
  for (; i < deg; i += 4){
    int s0 = csr_src[start + i];
    float e0 = __expf(lrelu(alpha_s[(size_t)s0*H + hm] + ad_m));
    edge(s0, e0);
  }

  // reduce across the 4 edge groups
#pragma unroll
  for (int off = 16; off < 64; off <<= 1){
    ssum += __shfl_xor(ssum, off);
#pragma unroll
    for (int k = 0; k < 8; ++k) acc[k] += __shfl_xor(acc[k], off);
  }

  if (lane < 16){
    float inv = 1.0f / ssum;
    float o[8];
#pragma unroll
    for (int k = 0; k < 8; ++k) o[k] = acc[k] * inv;
    if (LAYER1){
      float4 b0 = *(const float4*)(bias + ch);
      float4 b1 = *(const float4*)(bias + ch + 4);
      float bb[8] = {b0.x,b0.y,b0.z,b0.w,b1.x,b1.y,b1.z,b1.w};
#pragma unroll
      for (int k = 0; k < 8; ++k){
        float v = o[k] + bb[k];
        o[k] = (v > 0.f) ? v : expm1f(v);             // ELU
      }
    }
    half8 ho;
#pragma unroll
    for (int k = 0; k < 8; ++k) ho[k] = (_Float16)o[k];
    *(half8*)(outh + (size_t)n*128 + ch) = ho;

    if (LAYER1){
      float4 s0 = *(const float4*)(w2s + ch);
      float4 s1 = *(const float4*)(w2s + ch + 4);
      float4 d0 = *(const float4*)(w2d + ch);
      float4 d1 = *(const float4*)(w2d + ch + 4);
      float ps = o[0]*s0.x + o[1]*s0.y + o[2]*s0.z + o[3]*s0.w
               + o[4]*s1.x + o[5]*s1.y + o[6]*s1.z + o[7]*s1.w;
      float pd = o[0]*d0.x + o[1]*d0.y + o[2]*d0.z + o[3]*d0.w
               + o[4]*d1.x + o[5]*d1.y + o[6]*d1.z + o[7]*d1.w;
#pragma unroll
      for (int off = 1; off < 16; off <<= 1){
        ps += __shfl_xor(ps, off);
        pd += __shfl_xor(pd, off);
      }
      if (l == 0){
        as2[n] = ps;
        ad2[n] = pd;
      }
    }
  }
}

extern "C" void kernel_launch(void* const* d_in, const int* in_sizes, int n_in,
                              void* d_out, int out_size, void* d_ws, size_t ws_size,
                              hipStream_t stream){
  const float* x      = (const float*)d_in[0];
  const int*   ei     = (const int*)  d_in[1];
  const float* W1     = (const float*)d_in[2];
  const float* a_src1 = (const float*)d_in[3];
  const float* a_dst1 = (const float*)d_in[4];
  const float* b1     = (const float*)d_in[5];
  const float* W2     = (const float*)d_in[6];
  const float* a_src2 = (const float*)d_in[7];
  const float* a_dst2 = (const float*)d_in[8];
  const float* b2     = (const float*)d_in[9];
  float* out = (float*)d_out;

  const int N = in_sizes[0] / 128;
  const int E = in_sizes[1] / 2;
  const int* src = ei;
  const int* dst = ei + E;

  char* ws = (char*)d_ws;
  size_t off = 0;
  auto alloc = [&](size_t bytes) -> void* {
    void* p = ws + off;
    off += (bytes + 255) & ~(size_t)255;
    return p;
  };
  _Float16* hb   = (_Float16*)alloc((size_t)N * 128 * 2);  // layer-1 h, reused as agg2
  _Float16* act  = (_Float16*)alloc((size_t)N * 128 * 2);  // layer-1 output (ELU'd)
  float* asb     = (float*)alloc((size_t)N * 8 * 4);
  float* adb     = (float*)alloc((size_t)N * 8 * 4);
  float* as2     = (float*)alloc((size_t)N * 4);
  float* ad2     = (float*)alloc((size_t)N * 4);
  _Float16* Wt1  = (_Float16*)alloc(16384 * 2);
  _Float16* Wt2  = (_Float16*)alloc(16384 * 2);
  float* w2s     = (float*)alloc(128 * 4);
  float* w2d     = (float*)alloc(128 * 4);
  int*   csr     = (int*)  alloc((size_t)E * 4);
  int*   rowptr  = (int*)  alloc((size_t)(N + 1) * 4);
  int*   cursor  = (int*)  alloc((size_t)(N + 1) * 4);
  int*   deg     = (int*)  alloc((size_t)N * 4);
  int*   bsum    = (int*)  alloc(4096);

  hipMemsetAsync(deg, 0, (size_t)N * 4, stream);

  const int nb = (N + 1023) / 1024;
  const int rangeSize = (N + 7) / 8;
  prep_kernel   <<<3, 256, 0, stream>>>(W1, W2, a_src2, a_dst2, Wt1, Wt2, w2s, w2d);
  hist_kernel   <<<2048, 256, 0, stream>>>(dst, E, deg, rangeSize);
  scan1_kernel  <<<nb, 256, 0, stream>>>(deg, N, rowptr, bsum);
  scan2_kernel  <<<1, 64, 0, stream>>>(bsum, nb);
  scan3_kernel  <<<(N + 255)/256, 256, 0, stream>>>(rowptr, bsum, cursor, N);
  scatter_kernel<<<2048, 256, 0, stream>>>(src, dst, E, cursor, csr, rangeSize);

  const int gBlocks  = (N + 127) / 128;
  const int nBlocks4 = (N + 3) / 4;

  // layer 1: h1 = x@W1 (f16 MFMA) + alpha1 epilogue
  gemm_mfma<8, true, false><<<gBlocks, 256, 0, stream>>>(
      x, Wt1, hb, nullptr, a_src1, a_dst1, asb, adb, N);
  // agg1: act = ELU(P1 . h1 + b1), fused alpha2 = act . (W2^T a2)
  agg_kernel<8, true><<<nBlocks4, 256, 0, stream>>>(
      hb, asb, adb, rowptr, csr, b1, w2s, w2d, act, as2, ad2, N);
  // agg2 = P2 . act (normalized), into hb (dead)
  agg_kernel<1, false><<<nBlocks4, 256, 0, stream>>>(
      act, as2, ad2, rowptr, csr, nullptr, nullptr, nullptr, hb, nullptr, nullptr, N);
  // out = agg2 @ W2 + b2 (f32 out)
  gemm_mfma<0, false, true><<<gBlocks, 256, 0, stream>>>(
      hb, Wt2, out, b2, nullptr, nullptr, nullptr, nullptr, N);
}

// Round 11
// 366.386 us; speedup vs baseline: 1.0658x; 1.0249x over previous
//
#include <hip/hip_runtime.h>
#include <hip/hip_bf16.h>
#include <math.h>

#define NEG_SLOPE 0.2f

typedef _Float16 half8 __attribute__((ext_vector_type(8)));
typedef _Float16 half4 __attribute__((ext_vector_type(4)));
typedef _Float16 half2v __attribute__((ext_vector_type(2)));
typedef float f32x4 __attribute__((ext_vector_type(4)));

__device__ __forceinline__ float lrelu(float x){ return fmaxf(x, NEG_SLOPE * x); }

// ---------------- CSR build (XCD-partitioned by dst range) ----------------
__global__ void hist_kernel(const int* __restrict__ dst, int E,
                            int* __restrict__ deg, int rangeSize){
  const int x   = blockIdx.x & 7;
  const int gb  = blockIdx.x >> 3;
  const int nGB = gridDim.x >> 3;
  const int lo = x * rangeSize, hi = lo + rangeSize;
  const int stride = nGB * blockDim.x;
  for (int i = gb * blockDim.x + threadIdx.x; i < E; i += stride){
    int d = dst[i];
    if (d >= lo && d < hi) atomicAdd(&deg[d], 1);
  }
}

__global__ void scan1_kernel(const int* __restrict__ deg, int N,
                             int* __restrict__ rowptr, int* __restrict__ bsum){
  __shared__ int sdata[256];
  int t = threadIdx.x;
  int base = blockIdx.x * 1024;
  int v[4];
  int run = 0;
#pragma unroll
  for (int j = 0; j < 4; ++j){
    int idx = base + t*4 + j;
    int d = (idx < N) ? deg[idx] : 0;
    run += d;
    v[j] = run;
  }
  sdata[t] = run;
  __syncthreads();
  for (int off = 1; off < 256; off <<= 1){
    int x = (t >= off) ? sdata[t - off] : 0;
    __syncthreads();
    sdata[t] += x;
    __syncthreads();
  }
  int prev = (t > 0) ? sdata[t-1] : 0;
#pragma unroll
  for (int j = 0; j < 4; ++j){
    int idx = base + t*4 + j;
    if (idx < N) rowptr[idx + 1] = v[j] + prev;
  }
  if (t == 255) bsum[blockIdx.x] = sdata[255];
}

__global__ void scan2_kernel(int* __restrict__ bsum, int nb){
  if (threadIdx.x == 0 && blockIdx.x == 0){
    int run = 0;
    for (int i = 0; i < nb; ++i){ int x = bsum[i]; bsum[i] = run; run += x; }
  }
}

// also fills cursor[] = final rowptr[] so scatter can atomicAdd it directly
__global__ void scan3_kernel(int* __restrict__ rowptr, const int* __restrict__ bsum,
                             int* __restrict__ cursor, int N){
  int i = blockIdx.x * blockDim.x + threadIdx.x;
  if (i == 0){ rowptr[0] = 0; cursor[0] = 0; }
  if (i < N){
    int v = rowptr[i + 1] + bsum[i >> 10];
    rowptr[i + 1] = v;
    cursor[i + 1] = v;
  }
}

__global__ void scatter_kernel(const int* __restrict__ src, const int* __restrict__ dst, int E,
                               int* __restrict__ cursor, int* __restrict__ csr_src, int rangeSize){
  const int x   = blockIdx.x & 7;
  const int gb  = blockIdx.x >> 3;
  const int nGB = gridDim.x >> 3;
  const int lo = x * rangeSize, hi = lo + rangeSize;
  const int stride = nGB * blockDim.x;
  for (int i = gb * blockDim.x + threadIdx.x; i < E; i += stride){
    int d = dst[i];
    if (d >= lo && d < hi){
      int pos = atomicAdd(&cursor[d], 1);
      csr_src[pos] = src[i];
    }
  }
}

// ---------------- prep: Wt (f16 transposed) for both layers + w2s/w2d ----------------
__global__ void prep_kernel(const float* __restrict__ W1, const float* __restrict__ W2,
                            const float* __restrict__ as2, const float* __restrict__ ad2,
                            _Float16* __restrict__ Wt1, _Float16* __restrict__ Wt2,
                            float* __restrict__ w2s, float* __restrict__ w2d){
  int t = threadIdx.x;
  if (blockIdx.x < 2){
    const float* W = blockIdx.x ? W2 : W1;
    _Float16* Wt = blockIdx.x ? Wt2 : Wt1;
    for (int i = 0; i < 64; ++i){
      int e = i*256 + t;
      int k = e >> 7, c = e & 127;
      Wt[c*128 + k] = (_Float16)W[e];
    }
  } else {
    if (t < 128){
      float ps = 0.f, pd = 0.f;
      for (int c = 0; c < 128; ++c){
        float w = W2[t*128 + c];
        ps += w * as2[c];
        pd += w * ad2[c];
      }
      w2s[t] = ps;
      w2d[t] = pd;
    }
  }
}

// ---------------- MFMA f16 GEMM: h[N,128] = A[N,128] @ W[128,128] ----------------
// ALPHA_H==8: alpha_s written as f16 (halves alpha-gather footprint in agg), alpha_d f32.
template<int ALPHA_H, bool CASTF32, bool OUTF32>
__launch_bounds__(256, 2)
__global__ void gemm_mfma(const void* __restrict__ Aptr, const _Float16* __restrict__ Wt,
                          void* __restrict__ outp, const float* __restrict__ bias,
                          const float* __restrict__ a_src, const float* __restrict__ a_dst,
                          void* __restrict__ alpha_s_p, float* __restrict__ alpha_d, int N){
  __shared__ __align__(16) _Float16 Xs[128*128];
  __shared__ __align__(16) _Float16 Ws[128*128];
  __shared__ float apart[2][128][2];
  const int t = threadIdx.x;
  const int lane = t & 63;
  const int w = t >> 6;
  const int wr = w & 1, wc = w >> 1;
  const int rowBase = blockIdx.x * 128;
  const int lrow = lane & 15, lk = lane >> 4;

  if (CASTF32){
    const float* A = (const float*)Aptr;
#pragma unroll
    for (int p = 0; p < 16; ++p){
      int flat = p*256 + t;
      int row = flat >> 5, seg = flat & 31;
      int gr = rowBase + row;
      float4 v = (gr < N) ? *(const float4*)(A + (size_t)gr*128 + seg*4)
                          : make_float4(0.f,0.f,0.f,0.f);
      half4 hv = {(_Float16)v.x, (_Float16)v.y, (_Float16)v.z, (_Float16)v.w};
      int byt = (row*256 + seg*8) ^ ((row & 7) << 4);
      *(half4*)((char*)Xs + byt) = hv;
    }
  } else {
    const _Float16* A = (const _Float16*)Aptr;
#pragma unroll
    for (int p = 0; p < 8; ++p){
      int flat = p*256 + t;
      int row = flat >> 4, seg = flat & 15;
      int gr = rowBase + row;
      int4 v = (gr < N) ? *(const int4*)(A + (size_t)gr*128 + seg*8)
                        : make_int4(0,0,0,0);
      int byt = (row*256 + seg*16) ^ ((row & 7) << 4);
      *(int4*)((char*)Xs + byt) = v;
    }
  }
#pragma unroll
  for (int p = 0; p < 8; ++p){
    int flat = p*256 + t;
    int row = flat >> 4, seg = flat & 15;
    int4 v = *(const int4*)(Wt + row*128 + seg*8);
    int byt = (row*256 + seg*16) ^ ((row & 7) << 4);
    *(int4*)((char*)Ws + byt) = v;
  }
  __syncthreads();

  f32x4 acc[4][4];
#pragma unroll
  for (int mf = 0; mf < 4; ++mf)
#pragma unroll
    for (int nf = 0; nf < 4; ++nf) acc[mf][nf] = (f32x4){0.f,0.f,0.f,0.f};

#pragma unroll
  for (int ks = 0; ks < 4; ++ks){
    const int kbyte = ks*64 + lk*16;
    half8 b[4], a[4];
#pragma unroll
    for (int nf = 0; nf < 4; ++nf){
      int row = wr*64 + nf*16 + lrow;
      b[nf] = *(const half8*)((const char*)Xs + ((row*256 + kbyte) ^ ((row & 7) << 4)));
    }
#pragma unroll
    for (int mf = 0; mf < 4; ++mf){
      int col = wc*64 + mf*16 + lrow;
      a[mf] = *(const half8*)((const char*)Ws + ((col*256 + kbyte) ^ ((col & 7) << 4)));
    }
#pragma unroll
    for (int mf = 0; mf < 4; ++mf)
#pragma unroll
      for (int nf = 0; nf < 4; ++nf)
        acc[mf][nf] = __builtin_amdgcn_mfma_f32_16x16x32_f16(a[mf], b[nf], acc[mf][nf], 0, 0, 0);
  }

  if (OUTF32){
    float* outf = (float*)outp;
    float4 b4[4];
#pragma unroll
    for (int mf = 0; mf < 4; ++mf)
      b4[mf] = *(const float4*)(bias + wc*64 + mf*16 + lk*4);
#pragma unroll
    for (int nf = 0; nf < 4; ++nf){
      int row = rowBase + wr*64 + nf*16 + lrow;
      if (row < N){
#pragma unroll
        for (int mf = 0; mf < 4; ++mf){
          int col = wc*64 + mf*16 + lk*4;
          f32x4 v = acc[mf][nf];
          float4 st = make_float4(v.x + b4[mf].x, v.y + b4[mf].y, v.z + b4[mf].z, v.w + b4[mf].w);
          *(float4*)(outf + (size_t)row*128 + col) = st;
        }
      }
    }
  } else {
    _Float16* hout = (_Float16*)outp;
#pragma unroll
    for (int nf = 0; nf < 4; ++nf){
      int row = rowBase + wr*64 + nf*16 + lrow;
      if (row < N){
#pragma unroll
        for (int mf = 0; mf < 4; ++mf){
          int col = wc*64 + mf*16 + lk*4;
          f32x4 v = acc[mf][nf];
          half4 hv = {(_Float16)v.x, (_Float16)v.y, (_Float16)v.z, (_Float16)v.w};
          *(half4*)(hout + (size_t)row*128 + col) = hv;
        }
      }
    }
  }

  if (ALPHA_H > 0){
    float4 as4[4], ad4[4];
#pragma unroll
    for (int mf = 0; mf < 4; ++mf){
      int cb = wc*64 + mf*16 + lk*4;
      as4[mf] = *(const float4*)(a_src + cb);
      ad4[mf] = *(const float4*)(a_dst + cb);
    }
    if (ALPHA_H == 8){
      _Float16* alpha_s16 = (_Float16*)alpha_s_p;
#pragma unroll
      for (int nf = 0; nf < 4; ++nf){
        int row = rowBase + wr*64 + nf*16 + lrow;
#pragma unroll
        for (int mf = 0; mf < 4; ++mf){
          f32x4 v = acc[mf][nf];
          float ps = v.x*as4[mf].x + v.y*as4[mf].y + v.z*as4[mf].z + v.w*as4[mf].w;
          float pd = v.x*ad4[mf].x + v.y*ad4[mf].y + v.z*ad4[mf].z + v.w*ad4[mf].w;
          ps += __shfl_xor(ps, 16); ps += __shfl_xor(ps, 32);
          pd += __shfl_xor(pd, 16); pd += __shfl_xor(pd, 32);
          if (lane < 16 && row < N){
            int head = wc*4 + mf;
            alpha_s16[(size_t)row*8 + head] = (_Float16)ps;
            alpha_d[(size_t)row*8 + head] = pd;
          }
        }
      }
    } else {
      float* alpha_s = (float*)alpha_s_p;
#pragma unroll
      for (int nf = 0; nf < 4; ++nf){
        float ps = 0.f, pd = 0.f;
#pragma unroll
        for (int mf = 0; mf < 4; ++mf){
          f32x4 v = acc[mf][nf];
          ps += v.x*as4[mf].x + v.y*as4[mf].y + v.z*as4[mf].z + v.w*as4[mf].w;
          pd += v.x*ad4[mf].x + v.y*ad4[mf].y + v.z*ad4[mf].z + v.w*ad4[mf].w;
        }
        ps += __shfl_xor(ps, 16); ps += __shfl_xor(ps, 32);
        pd += __shfl_xor(pd, 16); pd += __shfl_xor(pd, 32);
        if (lane < 16){
          int rl = wr*64 + nf*16 + lane;
          apart[0][rl][wc] = ps;
          apart[1][rl][wc] = pd;
        }
      }
      __syncthreads();
      if (wc == 0){
        int rl = wr*64 + lane;
        int row = rowBase + rl;
        if (row < N){
          alpha_s[row] = apart[0][rl][0] + apart[0][rl][1];
          alpha_d[row] = apart[1][rl][0] + apart[1][rl][1];
        }
      }
    }
  }
}

// ---------------- softmax-aggregation (R6 structure: 2x unrolled gather) ----------------
// One wave per node; 4 edge-groups x 16 lanes x 8 channels; self-loop peeled to
// group 3; 2 independent csr->alpha->h chains per body. f32 softmax numerics.
// H=8 reads alpha_s as f16; H=1 (layer2) as f32.
template<int H, bool LAYER1>
__launch_bounds__(256)
__global__ void agg_kernel(const _Float16* __restrict__ hb, const void* __restrict__ alpha_s_p,
                           const float* __restrict__ alpha_d,
                           const int* __restrict__ rowptr, const int* __restrict__ csr_src,
                           const float* __restrict__ bias,
                           const float* __restrict__ w2s, const float* __restrict__ w2d,
                           _Float16* __restrict__ outh,
                           float* __restrict__ as2, float* __restrict__ ad2, int N){
  const int wid = threadIdx.x >> 6, lane = threadIdx.x & 63;
  const int n = blockIdx.x * 4 + wid;
  if (n >= N) return;
  const int start = rowptr[n];
  const int deg = rowptr[n + 1] - start;

  const int g  = lane >> 4;
  const int l  = lane & 15;
  const int ch = l * 8;
  const int hm = (H == 8) ? (l >> 1) : 0;
  const float ad_m = alpha_d[(size_t)n*H + hm];
  const _Float16* as16 = (const _Float16*)alpha_s_p;
  const float*    as32 = (const float*)alpha_s_p;

  auto alphaS = [&](int s) -> float {
    return (H == 8) ? (float)as16[(size_t)s*8 + hm] : as32[s];
  };

  float acc[8];
#pragma unroll
  for (int k = 0; k < 8; ++k) acc[k] = 0.f;
  float ssum = 0.f;

  auto edge = [&](int s, float ex){
    int4 hv = *(const int4*)(hb + ((size_t)s << 7) + ch);
    half2v h0 = __builtin_bit_cast(half2v, hv.x);
    half2v h1 = __builtin_bit_cast(half2v, hv.y);
    half2v h2 = __builtin_bit_cast(half2v, hv.z);
    half2v h3 = __builtin_bit_cast(half2v, hv.w);
    acc[0] += (float)h0.x * ex; acc[1] += (float)h0.y * ex;
    acc[2] += (float)h1.x * ex; acc[3] += (float)h1.y * ex;
    acc[4] += (float)h2.x * ex; acc[5] += (float)h2.y * ex;
    acc[6] += (float)h3.x * ex; acc[7] += (float)h3.y * ex;
    ssum += ex;
  };

  // self-loop (group 3)
  if (g == 3){
    float ex = __expf(lrelu(alphaS(n) + ad_m));
    edge(n, ex);
  }

  int i = g;
  // 2x unrolled: two independent csr->alpha->h chains in flight (8 edges/body)
  for (; i + 4 < deg; i += 8){
    int s0 = csr_src[start + i];
    int s1 = csr_src[start + i + 4];
    float a0 = alphaS(s0);
    float a1 = alphaS(s1);
    float e0 = __expf(fmaxf(a0 + ad_m, NEG_SLOPE * (a0 + ad_m)));
    float e1 = __expf(fmaxf(a1 + ad_m, NEG_SLOPE * (a1 + ad_m)));
    edge(s0, e0);
    edge(s1, e1);
  }
  if (i < deg){
    int s0 = csr_src[start + i];
    float e0 = __expf(lrelu(alphaS(s0) + ad_m));
    edge(s0, e0);
  }

  // reduce across the 4 edge groups
#pragma unroll
  for (int off = 16; off < 64; off <<= 1){
    ssum += __shfl_xor(ssum, off);
#pragma unroll
    for (int k = 0; k < 8; ++k) acc[k] += __shfl_xor(acc[k], off);
  }

  if (lane < 16){
    float inv = 1.0f / ssum;
    float o[8];
#pragma unroll
    for (int k = 0; k < 8; ++k) o[k] = acc[k] * inv;
    if (LAYER1){
      float4 b0 = *(const float4*)(bias + ch);
      float4 b1 = *(const float4*)(bias + ch + 4);
      float bb[8] = {b0.x,b0.y,b0.z,b0.w,b1.x,b1.y,b1.z,b1.w};
#pragma unroll
      for (int k = 0; k < 8; ++k){
        float v = o[k] + bb[k];
        o[k] = (v > 0.f) ? v : expm1f(v);             // ELU
      }
    }
    half8 ho;
#pragma unroll
    for (int k = 0; k < 8; ++k) ho[k] = (_Float16)o[k];
    *(half8*)(outh + (size_t)n*128 + ch) = ho;

    if (LAYER1){
      float4 s0 = *(const float4*)(w2s + ch);
      float4 s1 = *(const float4*)(w2s + ch + 4);
      float4 d0 = *(const float4*)(w2d + ch);
      float4 d1 = *(const float4*)(w2d + ch + 4);
      float ps = o[0]*s0.x + o[1]*s0.y + o[2]*s0.z + o[3]*s0.w
               + o[4]*s1.x + o[5]*s1.y + o[6]*s1.z + o[7]*s1.w;
      float pd = o[0]*d0.x + o[1]*d0.y + o[2]*d0.z + o[3]*d0.w
               + o[4]*d1.x + o[5]*d1.y + o[6]*d1.z + o[7]*d1.w;
#pragma unroll
      for (int off = 1; off < 16; off <<= 1){
        ps += __shfl_xor(ps, off);
        pd += __shfl_xor(pd, off);
      }
      if (l == 0){
        as2[n] = ps;
        ad2[n] = pd;
      }
    }
  }
}

extern "C" void kernel_launch(void* const* d_in, const int* in_sizes, int n_in,
                              void* d_out, int out_size, void* d_ws, size_t ws_size,
                              hipStream_t stream){
  const float* x      = (const float*)d_in[0];
  const int*   ei     = (const int*)  d_in[1];
  const float* W1     = (const float*)d_in[2];
  const float* a_src1 = (const float*)d_in[3];
  const float* a_dst1 = (const float*)d_in[4];
  const float* b1     = (const float*)d_in[5];
  const float* W2     = (const float*)d_in[6];
  const float* a_src2 = (const float*)d_in[7];
  const float* a_dst2 = (const float*)d_in[8];
  const float* b2     = (const float*)d_in[9];
  float* out = (float*)d_out;

  const int N = in_sizes[0] / 128;
  const int E = in_sizes[1] / 2;
  const int* src = ei;
  const int* dst = ei + E;

  char* ws = (char*)d_ws;
  size_t off = 0;
  auto alloc = [&](size_t bytes) -> void* {
    void* p = ws + off;
    off += (bytes + 255) & ~(size_t)255;
    return p;
  };
  _Float16* hb   = (_Float16*)alloc((size_t)N * 128 * 2);  // layer-1 h, reused as agg2
  _Float16* act  = (_Float16*)alloc((size_t)N * 128 * 2);  // layer-1 output (ELU'd)
  _Float16* asb  = (_Float16*)alloc((size_t)N * 8 * 2);    // layer-1 alpha_s (f16)
  float* adb     = (float*)alloc((size_t)N * 8 * 4);
  float* as2     = (float*)alloc((size_t)N * 4);
  float* ad2     = (float*)alloc((size_t)N * 4);
  _Float16* Wt1  = (_Float16*)alloc(16384 * 2);
  _Float16* Wt2  = (_Float16*)alloc(16384 * 2);
  float* w2s     = (float*)alloc(128 * 4);
  float* w2d     = (float*)alloc(128 * 4);
  int*   csr     = (int*)  alloc((size_t)E * 4);
  int*   rowptr  = (int*)  alloc((size_t)(N + 1) * 4);
  int*   cursor  = (int*)  alloc((size_t)(N + 1) * 4);
  int*   deg     = (int*)  alloc((size_t)N * 4);
  int*   bsum    = (int*)  alloc(4096);

  hipMemsetAsync(deg, 0, (size_t)N * 4, stream);

  const int nb = (N + 1023) / 1024;
  const int rangeSize = (N + 7) / 8;
  prep_kernel   <<<3, 256, 0, stream>>>(W1, W2, a_src2, a_dst2, Wt1, Wt2, w2s, w2d);
  hist_kernel   <<<2048, 256, 0, stream>>>(dst, E, deg, rangeSize);
  scan1_kernel  <<<nb, 256, 0, stream>>>(deg, N, rowptr, bsum);
  scan2_kernel  <<<1, 64, 0, stream>>>(bsum, nb);
  scan3_kernel  <<<(N + 255)/256, 256, 0, stream>>>(rowptr, bsum, cursor, N);
  scatter_kernel<<<2048, 256, 0, stream>>>(src, dst, E, cursor, csr, rangeSize);

  const int gBlocks  = (N + 127) / 128;
  const int nBlocks4 = (N + 3) / 4;

  // layer 1: h1 = x@W1 (f16 MFMA) + alpha1 epilogue (alpha_s f16)
  gemm_mfma<8, true, false><<<gBlocks, 256, 0, stream>>>(
      x, Wt1, hb, nullptr, a_src1, a_dst1, asb, adb, N);
  // agg1: act = ELU(P1 . h1 + b1), fused alpha2 = act . (W2^T a2)
  agg_kernel<8, true><<<nBlocks4, 256, 0, stream>>>(
      hb, asb, adb, rowptr, csr, b1, w2s, w2d, act, as2, ad2, N);
  // agg2 = P2 . act (normalized), into hb (dead)
  agg_kernel<1, false><<<nBlocks4, 256, 0, stream>>>(
      act, as2, ad2, rowptr, csr, nullptr, nullptr, nullptr, hb, nullptr, nullptr, N);
  // out = agg2 @ W2 + b2 (f32 out)
  gemm_mfma<0, false, true><<<gBlocks, 256, 0, stream>>>(
      hb, Wt2, out, b2, nullptr, nullptr, nullptr, nullptr, N);
}

// Round 12
// 354.585 us; speedup vs baseline: 1.1012x; 1.0333x over previous
//
#include <hip/hip_runtime.h>
#include <hip/hip_bf16.h>
#include <math.h>

#define NEG_SLOPE 0.2f

typedef _Float16 half8 __attribute__((ext_vector_type(8)));
typedef _Float16 half4 __attribute__((ext_vector_type(4)));
typedef _Float16 half2v __attribute__((ext_vector_type(2)));
typedef float f32x4 __attribute__((ext_vector_type(4)));

__device__ __forceinline__ float lrelu(float x){ return fmaxf(x, NEG_SLOPE * x); }

// ---------------- CSR build (XCD-partitioned by dst range) ----------------
__global__ void hist_kernel(const int* __restrict__ dst, int E,
                            int* __restrict__ deg, int rangeSize){
  const int x   = blockIdx.x & 7;
  const int gb  = blockIdx.x >> 3;
  const int nGB = gridDim.x >> 3;
  const int lo = x * rangeSize, hi = lo + rangeSize;
  const int stride = nGB * blockDim.x;
  for (int i = gb * blockDim.x + threadIdx.x; i < E; i += stride){
    int d = dst[i];
    if (d >= lo && d < hi) atomicAdd(&deg[d], 1);
  }
}

__global__ void scan1_kernel(const int* __restrict__ deg, int N,
                             int* __restrict__ rowptr, int* __restrict__ bsum){
  __shared__ int sdata[256];
  int t = threadIdx.x;
  int base = blockIdx.x * 1024;
  int v[4];
  int run = 0;
#pragma unroll
  for (int j = 0; j < 4; ++j){
    int idx = base + t*4 + j;
    int d = (idx < N) ? deg[idx] : 0;
    run += d;
    v[j] = run;
  }
  sdata[t] = run;
  __syncthreads();
  for (int off = 1; off < 256; off <<= 1){
    int x = (t >= off) ? sdata[t - off] : 0;
    __syncthreads();
    sdata[t] += x;
    __syncthreads();
  }
  int prev = (t > 0) ? sdata[t-1] : 0;
#pragma unroll
  for (int j = 0; j < 4; ++j){
    int idx = base + t*4 + j;
    if (idx < N) rowptr[idx + 1] = v[j] + prev;
  }
  if (t == 255) bsum[blockIdx.x] = sdata[255];
}

// wave-parallel exclusive scan of bsum (nb <= 128): 64 lanes, 2 elems/lane
__global__ void scan2_kernel(int* __restrict__ bsum, int nb){
  int lane = threadIdx.x;              // 64 threads
  int i0 = 2*lane, i1 = 2*lane + 1;
  int v0 = (i0 < nb) ? bsum[i0] : 0;
  int v1 = (i1 < nb) ? bsum[i1] : 0;
  int pair = v0 + v1;
  int s = pair;                         // inclusive scan of pair sums
#pragma unroll
  for (int off = 1; off < 64; off <<= 1){
    int t = __shfl_up(s, off);
    if (lane >= off) s += t;
  }
  int excl = s - pair;                  // exclusive prefix of this lane's pair
  if (i0 < nb) bsum[i0] = excl;
  if (i1 < nb) bsum[i1] = excl + v0;
}

// also fills cursor[] = final rowptr[] so scatter can atomicAdd it directly
__global__ void scan3_kernel(int* __restrict__ rowptr, const int* __restrict__ bsum,
                             int* __restrict__ cursor, int N){
  int i = blockIdx.x * blockDim.x + threadIdx.x;
  if (i == 0){ rowptr[0] = 0; cursor[0] = 0; }
  if (i < N){
    int v = rowptr[i + 1] + bsum[i >> 10];
    rowptr[i + 1] = v;
    cursor[i + 1] = v;
  }
}

__global__ void scatter_kernel(const int* __restrict__ src, const int* __restrict__ dst, int E,
                               int* __restrict__ cursor, int* __restrict__ csr_src, int rangeSize){
  const int x   = blockIdx.x & 7;
  const int gb  = blockIdx.x >> 3;
  const int nGB = gridDim.x >> 3;
  const int lo = x * rangeSize, hi = lo + rangeSize;
  const int stride = nGB * blockDim.x;
  for (int i = gb * blockDim.x + threadIdx.x; i < E; i += stride){
    int d = dst[i];
    if (d >= lo && d < hi){
      int pos = atomicAdd(&cursor[d], 1);
      csr_src[pos] = src[i];
    }
  }
}

// ---------------- prep: Wt (f16 transposed, LDS-staged coalesced) + w2s/w2d ----------------
__global__ void prep_kernel(const float* __restrict__ W1, const float* __restrict__ W2,
                            const float* __restrict__ as2, const float* __restrict__ ad2,
                            _Float16* __restrict__ Wt1, _Float16* __restrict__ Wt2,
                            float* __restrict__ w2s, float* __restrict__ w2d){
  __shared__ float Ld[128][129];
  int t = threadIdx.x;
  if (blockIdx.x < 2){
    const float* W = blockIdx.x ? W2 : W1;
    _Float16* Wt = blockIdx.x ? Wt2 : Wt1;
    // stage coalesced reads
#pragma unroll 4
    for (int i = 0; i < 64; ++i){
      int e = i*256 + t;
      Ld[e >> 7][e & 127] = W[e];
    }
    __syncthreads();
    // coalesced transposed writes from LDS
#pragma unroll 4
    for (int i = 0; i < 64; ++i){
      int o = i*256 + t;                // o = c*128 + k
      Wt[o] = (_Float16)Ld[o & 127][o >> 7];
    }
  } else {
    // stage W2 coalesced, then per-k dot with as2/ad2 from LDS
#pragma unroll 4
    for (int i = 0; i < 64; ++i){
      int e = i*256 + t;
      Ld[e >> 7][e & 127] = W2[e];
    }
    __syncthreads();
    if (t < 128){
      float ps = 0.f, pd = 0.f;
      for (int c = 0; c < 128; ++c){
        float w = Ld[t][c];
        ps += w * as2[c];
        pd += w * ad2[c];
      }
      w2s[t] = ps;
      w2d[t] = pd;
    }
  }
}

// ---------------- MFMA f16 GEMM: h[N,128] = A[N,128] @ W[128,128] ----------------
// ALPHA_H==8: alpha_s written as f16 (halves alpha-gather footprint in agg), alpha_d f32.
template<int ALPHA_H, bool CASTF32, bool OUTF32>
__launch_bounds__(256, 2)
__global__ void gemm_mfma(const void* __restrict__ Aptr, const _Float16* __restrict__ Wt,
                          void* __restrict__ outp, const float* __restrict__ bias,
                          const float* __restrict__ a_src, const float* __restrict__ a_dst,
                          void* __restrict__ alpha_s_p, float* __restrict__ alpha_d, int N){
  __shared__ __align__(16) _Float16 Xs[128*128];
  __shared__ __align__(16) _Float16 Ws[128*128];
  __shared__ float apart[2][128][2];
  const int t = threadIdx.x;
  const int lane = t & 63;
  const int w = t >> 6;
  const int wr = w & 1, wc = w >> 1;
  const int rowBase = blockIdx.x * 128;
  const int lrow = lane & 15, lk = lane >> 4;

  if (CASTF32){
    const float* A = (const float*)Aptr;
#pragma unroll
    for (int p = 0; p < 16; ++p){
      int flat = p*256 + t;
      int row = flat >> 5, seg = flat & 31;
      int gr = rowBase + row;
      float4 v = (gr < N) ? *(const float4*)(A + (size_t)gr*128 + seg*4)
                          : make_float4(0.f,0.f,0.f,0.f);
      half4 hv = {(_Float16)v.x, (_Float16)v.y, (_Float16)v.z, (_Float16)v.w};
      int byt = (row*256 + seg*8) ^ ((row & 7) << 4);
      *(half4*)((char*)Xs + byt) = hv;
    }
  } else {
    const _Float16* A = (const _Float16*)Aptr;
#pragma unroll
    for (int p = 0; p < 8; ++p){
      int flat = p*256 + t;
      int row = flat >> 4, seg = flat & 15;
      int gr = rowBase + row;
      int4 v = (gr < N) ? *(const int4*)(A + (size_t)gr*128 + seg*8)
                        : make_int4(0,0,0,0);
      int byt = (row*256 + seg*16) ^ ((row & 7) << 4);
      *(int4*)((char*)Xs + byt) = v;
    }
  }
#pragma unroll
  for (int p = 0; p < 8; ++p){
    int flat = p*256 + t;
    int row = flat >> 4, seg = flat & 15;
    int4 v = *(const int4*)(Wt + row*128 + seg*8);
    int byt = (row*256 + seg*16) ^ ((row & 7) << 4);
    *(int4*)((char*)Ws + byt) = v;
  }
  __syncthreads();

  f32x4 acc[4][4];
#pragma unroll
  for (int mf = 0; mf < 4; ++mf)
#pragma unroll
    for (int nf = 0; nf < 4; ++nf) acc[mf][nf] = (f32x4){0.f,0.f,0.f,0.f};

#pragma unroll
  for (int ks = 0; ks < 4; ++ks){
    const int kbyte = ks*64 + lk*16;
    half8 b[4], a[4];
#pragma unroll
    for (int nf = 0; nf < 4; ++nf){
      int row = wr*64 + nf*16 + lrow;
      b[nf] = *(const half8*)((const char*)Xs + ((row*256 + kbyte) ^ ((row & 7) << 4)));
    }
#pragma unroll
    for (int mf = 0; mf < 4; ++mf){
      int col = wc*64 + mf*16 + lrow;
      a[mf] = *(const half8*)((const char*)Ws + ((col*256 + kbyte) ^ ((col & 7) << 4)));
    }
#pragma unroll
    for (int mf = 0; mf < 4; ++mf)
#pragma unroll
      for (int nf = 0; nf < 4; ++nf)
        acc[mf][nf] = __builtin_amdgcn_mfma_f32_16x16x32_f16(a[mf], b[nf], acc[mf][nf], 0, 0, 0);
  }

  if (OUTF32){
    float* outf = (float*)outp;
    float4 b4[4];
#pragma unroll
    for (int mf = 0; mf < 4; ++mf)
      b4[mf] = *(const float4*)(bias + wc*64 + mf*16 + lk*4);
#pragma unroll
    for (int nf = 0; nf < 4; ++nf){
      int row = rowBase + wr*64 + nf*16 + lrow;
      if (row < N){
#pragma unroll
        for (int mf = 0; mf < 4; ++mf){
          int col = wc*64 + mf*16 + lk*4;
          f32x4 v = acc[mf][nf];
          float4 st = make_float4(v.x + b4[mf].x, v.y + b4[mf].y, v.z + b4[mf].z, v.w + b4[mf].w);
          *(float4*)(outf + (size_t)row*128 + col) = st;
        }
      }
    }
  } else {
    _Float16* hout = (_Float16*)outp;
#pragma unroll
    for (int nf = 0; nf < 4; ++nf){
      int row = rowBase + wr*64 + nf*16 + lrow;
      if (row < N){
#pragma unroll
        for (int mf = 0; mf < 4; ++mf){
          int col = wc*64 + mf*16 + lk*4;
          f32x4 v = acc[mf][nf];
          half4 hv = {(_Float16)v.x, (_Float16)v.y, (_Float16)v.z, (_Float16)v.w};
          *(half4*)(hout + (size_t)row*128 + col) = hv;
        }
      }
    }
  }

  if (ALPHA_H > 0){
    float4 as4[4], ad4[4];
#pragma unroll
    for (int mf = 0; mf < 4; ++mf){
      int cb = wc*64 + mf*16 + lk*4;
      as4[mf] = *(const float4*)(a_src + cb);
      ad4[mf] = *(const float4*)(a_dst + cb);
    }
    if (ALPHA_H == 8){
      _Float16* alpha_s16 = (_Float16*)alpha_s_p;
#pragma unroll
      for (int nf = 0; nf < 4; ++nf){
        int row = rowBase + wr*64 + nf*16 + lrow;
#pragma unroll
        for (int mf = 0; mf < 4; ++mf){
          f32x4 v = acc[mf][nf];
          float ps = v.x*as4[mf].x + v.y*as4[mf].y + v.z*as4[mf].z + v.w*as4[mf].w;
          float pd = v.x*ad4[mf].x + v.y*ad4[mf].y + v.z*ad4[mf].z + v.w*ad4[mf].w;
          ps += __shfl_xor(ps, 16); ps += __shfl_xor(ps, 32);
          pd += __shfl_xor(pd, 16); pd += __shfl_xor(pd, 32);
          if (lane < 16 && row < N){
            int head = wc*4 + mf;
            alpha_s16[(size_t)row*8 + head] = (_Float16)ps;
            alpha_d[(size_t)row*8 + head] = pd;
          }
        }
      }
    } else {
      float* alpha_s = (float*)alpha_s_p;
#pragma unroll
      for (int nf = 0; nf < 4; ++nf){
        float ps = 0.f, pd = 0.f;
#pragma unroll
        for (int mf = 0; mf < 4; ++mf){
          f32x4 v = acc[mf][nf];
          ps += v.x*as4[mf].x + v.y*as4[mf].y + v.z*as4[mf].z + v.w*as4[mf].w;
          pd += v.x*ad4[mf].x + v.y*ad4[mf].y + v.z*ad4[mf].z + v.w*ad4[mf].w;
        }
        ps += __shfl_xor(ps, 16); ps += __shfl_xor(ps, 32);
        pd += __shfl_xor(pd, 16); pd += __shfl_xor(pd, 32);
        if (lane < 16){
          int rl = wr*64 + nf*16 + lane;
          apart[0][rl][wc] = ps;
          apart[1][rl][wc] = pd;
        }
      }
      __syncthreads();
      if (wc == 0){
        int rl = wr*64 + lane;
        int row = rowBase + rl;
        if (row < N){
          alpha_s[row] = apart[0][rl][0] + apart[0][rl][1];
          alpha_d[row] = apart[1][rl][0] + apart[1][rl][1];
        }
      }
    }
  }
}

// ---------------- softmax-aggregation (R6 structure: 2x unrolled gather) ----------------
template<int H, bool LAYER1>
__launch_bounds__(256)
__global__ void agg_kernel(const _Float16* __restrict__ hb, const void* __restrict__ alpha_s_p,
                           const float* __restrict__ alpha_d,
                           const int* __restrict__ rowptr, const int* __restrict__ csr_src,
                           const float* __restrict__ bias,
                           const float* __restrict__ w2s, const float* __restrict__ w2d,
                           _Float16* __restrict__ outh,
                           float* __restrict__ as2, float* __restrict__ ad2, int N){
  const int wid = threadIdx.x >> 6, lane = threadIdx.x & 63;
  const int n = blockIdx.x * 4 + wid;
  if (n >= N) return;
  const int start = rowptr[n];
  const int deg = rowptr[n + 1] - start;

  const int g  = lane >> 4;
  const int l  = lane & 15;
  const int ch = l * 8;
  const int hm = (H == 8) ? (l >> 1) : 0;
  const float ad_m = alpha_d[(size_t)n*H + hm];
  const _Float16* as16 = (const _Float16*)alpha_s_p;
  const float*    as32 = (const float*)alpha_s_p;

  auto alphaS = [&](int s) -> float {
    return (H == 8) ? (float)as16[(size_t)s*8 + hm] : as32[s];
  };

  float acc[8];
#pragma unroll
  for (int k = 0; k < 8; ++k) acc[k] = 0.f;
  float ssum = 0.f;

  auto edge = [&](int s, float ex){
    int4 hv = *(const int4*)(hb + ((size_t)s << 7) + ch);
    half2v h0 = __builtin_bit_cast(half2v, hv.x);
    half2v h1 = __builtin_bit_cast(half2v, hv.y);
    half2v h2 = __builtin_bit_cast(half2v, hv.z);
    half2v h3 = __builtin_bit_cast(half2v, hv.w);
    acc[0] += (float)h0.x * ex; acc[1] += (float)h0.y * ex;
    acc[2] += (float)h1.x * ex; acc[3] += (float)h1.y * ex;
    acc[4] += (float)h2.x * ex; acc[5] += (float)h2.y * ex;
    acc[6] += (float)h3.x * ex; acc[7] += (float)h3.y * ex;
    ssum += ex;
  };

  // self-loop (group 3)
  if (g == 3){
    float ex = __expf(lrelu(alphaS(n) + ad_m));
    edge(n, ex);
  }

  int i = g;
  // 2x unrolled: two independent csr->alpha->h chains in flight (8 edges/body)
  for (; i + 4 < deg; i += 8){
    int s0 = csr_src[start + i];
    int s1 = csr_src[start + i + 4];
    float a0 = alphaS(s0);
    float a1 = alphaS(s1);
    float e0 = __expf(fmaxf(a0 + ad_m, NEG_SLOPE * (a0 + ad_m)));
    float e1 = __expf(fmaxf(a1 + ad_m, NEG_SLOPE * (a1 + ad_m)));
    edge(s0, e0);
    edge(s1, e1);
  }
  if (i < deg){
    int s0 = csr_src[start + i];
    float e0 = __expf(lrelu(alphaS(s0) + ad_m));
    edge(s0, e0);
  }

  // reduce across the 4 edge groups
#pragma unroll
  for (int off = 16; off < 64; off <<= 1){
    ssum += __shfl_xor(ssum, off);
#pragma unroll
    for (int k = 0; k < 8; ++k) acc[k] += __shfl_xor(acc[k], off);
  }

  if (lane < 16){
    float inv = 1.0f / ssum;
    float o[8];
#pragma unroll
    for (int k = 0; k < 8; ++k) o[k] = acc[k] * inv;
    if (LAYER1){
      float4 b0 = *(const float4*)(bias + ch);
      float4 b1 = *(const float4*)(bias + ch + 4);
      float bb[8] = {b0.x,b0.y,b0.z,b0.w,b1.x,b1.y,b1.z,b1.w};
#pragma unroll
      for (int k = 0; k < 8; ++k){
        float v = o[k] + bb[k];
        o[k] = (v > 0.f) ? v : expm1f(v);             // ELU
      }
    }
    half8 ho;
#pragma unroll
    for (int k = 0; k < 8; ++k) ho[k] = (_Float16)o[k];
    *(half8*)(outh + (size_t)n*128 + ch) = ho;

    if (LAYER1){
      float4 s0 = *(const float4*)(w2s + ch);
      float4 s1 = *(const float4*)(w2s + ch + 4);
      float4 d0 = *(const float4*)(w2d + ch);
      float4 d1 = *(const float4*)(w2d + ch + 4);
      float ps = o[0]*s0.x + o[1]*s0.y + o[2]*s0.z + o[3]*s0.w
               + o[4]*s1.x + o[5]*s1.y + o[6]*s1.z + o[7]*s1.w;
      float pd = o[0]*d0.x + o[1]*d0.y + o[2]*d0.z + o[3]*d0.w
               + o[4]*d1.x + o[5]*d1.y + o[6]*d1.z + o[7]*d1.w;
#pragma unroll
      for (int off = 1; off < 16; off <<= 1){
        ps += __shfl_xor(ps, off);
        pd += __shfl_xor(pd, off);
      }
      if (l == 0){
        as2[n] = ps;
        ad2[n] = pd;
      }
    }
  }
}

extern "C" void kernel_launch(void* const* d_in, const int* in_sizes, int n_in,
                              void* d_out, int out_size, void* d_ws, size_t ws_size,
                              hipStream_t stream){
  const float* x      = (const float*)d_in[0];
  const int*   ei     = (const int*)  d_in[1];
  const float* W1     = (const float*)d_in[2];
  const float* a_src1 = (const float*)d_in[3];
  const float* a_dst1 = (const float*)d_in[4];
  const float* b1     = (const float*)d_in[5];
  const float* W2     = (const float*)d_in[6];
  const float* a_src2 = (const float*)d_in[7];
  const float* a_dst2 = (const float*)d_in[8];
  const float* b2     = (const float*)d_in[9];
  float* out = (float*)d_out;

  const int N = in_sizes[0] / 128;
  const int E = in_sizes[1] / 2;
  const int* src = ei;
  const int* dst = ei + E;

  char* ws = (char*)d_ws;
  size_t off = 0;
  auto alloc = [&](size_t bytes) -> void* {
    void* p = ws + off;
    off += (bytes + 255) & ~(size_t)255;
    return p;
  };
  _Float16* hb   = (_Float16*)alloc((size_t)N * 128 * 2);  // layer-1 h, reused as agg2
  _Float16* act  = (_Float16*)alloc((size_t)N * 128 * 2);  // layer-1 output (ELU'd)
  _Float16* asb  = (_Float16*)alloc((size_t)N * 8 * 2);    // layer-1 alpha_s (f16)
  float* adb     = (float*)alloc((size_t)N * 8 * 4);
  float* as2     = (float*)alloc((size_t)N * 4);
  float* ad2     = (float*)alloc((size_t)N * 4);
  _Float16* Wt1  = (_Float16*)alloc(16384 * 2);
  _Float16* Wt2  = (_Float16*)alloc(16384 * 2);
  float* w2s     = (float*)alloc(128 * 4);
  float* w2d     = (float*)alloc(128 * 4);
  int*   csr     = (int*)  alloc((size_t)E * 4);
  int*   rowptr  = (int*)  alloc((size_t)(N + 1) * 4);
  int*   cursor  = (int*)  alloc((size_t)(N + 1) * 4);
  int*   deg     = (int*)  alloc((size_t)N * 4);
  int*   bsum    = (int*)  alloc(4096);

  hipMemsetAsync(deg, 0, (size_t)N * 4, stream);

  const int nb = (N + 1023) / 1024;
  const int rangeSize = (N + 7) / 8;
  prep_kernel   <<<3, 256, 0, stream>>>(W1, W2, a_src2, a_dst2, Wt1, Wt2, w2s, w2d);
  hist_kernel   <<<2048, 256, 0, stream>>>(dst, E, deg, rangeSize);
  scan1_kernel  <<<nb, 256, 0, stream>>>(deg, N, rowptr, bsum);
  scan2_kernel  <<<1, 64, 0, stream>>>(bsum, nb);
  scan3_kernel  <<<(N + 255)/256, 256, 0, stream>>>(rowptr, bsum, cursor, N);
  scatter_kernel<<<2048, 256, 0, stream>>>(src, dst, E, cursor, csr, rangeSize);

  const int gBlocks  = (N + 127) / 128;
  const int nBlocks4 = (N + 3) / 4;

  // layer 1: h1 = x@W1 (f16 MFMA) + alpha1 epilogue (alpha_s f16)
  gemm_mfma<8, true, false><<<gBlocks, 256, 0, stream>>>(
      x, Wt1, hb, nullptr, a_src1, a_dst1, asb, adb, N);
  // agg1: act = ELU(P1 . h1 + b1), fused alpha2 = act . (W2^T a2)
  agg_kernel<8, true><<<nBlocks4, 256, 0, stream>>>(
      hb, asb, adb, rowptr, csr, b1, w2s, w2d, act, as2, ad2, N);
  // agg2 = P2 . act (normalized), into hb (dead)
  agg_kernel<1, false><<<nBlocks4, 256, 0, stream>>>(
      act, as2, ad2, rowptr, csr, nullptr, nullptr, nullptr, hb, nullptr, nullptr, N);
  // out = agg2 @ W2 + b2 (f32 out)
  gemm_mfma<0, false, true><<<gBlocks, 256, 0, stream>>>(
      hb, Wt2, out, b2, nullptr, nullptr, nullptr, nullptr, N);
}